// Round 1
// 1009.210 us; speedup vs baseline: 1.1579x; 1.1579x over previous
//
#include <hip/hip_runtime.h>
#include <math.h>

#define HIDDEN 4096
#define NH 32
#define NKV 8
#define HD 128
#define BBATCH 2
#define SEQ 2048
#define BS 4096     // BBATCH*SEQ
#define QKVD 6144   // merged QKV projection row stride (shorts): 4096 Q + 1024 K + 1024 V

typedef __attribute__((ext_vector_type(8))) short short8;
typedef __attribute__((ext_vector_type(4))) float f32x4;
typedef __attribute__((ext_vector_type(4))) unsigned int uint4v;

__device__ __forceinline__ unsigned short f2bf(float f) {
  union { float f; unsigned int u; } v; v.f = f;
  unsigned int r = v.u + 0x7fffu + ((v.u >> 16) & 1u);
  return (unsigned short)(r >> 16);
}
__device__ __forceinline__ float bf2f(unsigned short u) {
  union { unsigned int u; float f; } v; v.u = ((unsigned int)u) << 16;
  return v.f;
}
// pack two f32 -> dword of 2 bf16 (RNE), single VALU op vs ~5 for emulated f2bf
__device__ __forceinline__ unsigned int cvtpk(float lo, float hi) {
  unsigned int r;
  asm("v_cvt_pk_bf16_f32 %0, %1, %2" : "=v"(r) : "v"(lo), "v"(hi));
  return r;
}

// async global->LDS, 16B per lane. LDS dest must be uniform base + lane*16.
__device__ __forceinline__ void gload16(const unsigned short* g, unsigned short* l) {
  __builtin_amdgcn_global_load_lds((const __attribute__((address_space(1))) unsigned int*)(const void*)g,
                                   (__attribute__((address_space(3))) unsigned int*)(void*)l, 16, 0, 0);
}

// ---------------- fp32 -> bf16 cast ----------------
__global__ void cast_f32_bf16(const float* __restrict__ in, unsigned short* __restrict__ out) {
  int i = (blockIdx.x * blockDim.x + threadIdx.x) * 4;
  float4 f = *(const float4*)(in + i);
  ushort4 u;
  u.x = f2bf(f.x); u.y = f2bf(f.y); u.z = f2bf(f.z); u.w = f2bf(f.w);
  *(ushort4*)(out + i) = u;
}

// ---------------- GEMM m97-style: C[M,N] = A[M,K]*Bm[N,K]^T, 128x128 tile ----------------
template<int OUT_F32>
__global__ __launch_bounds__(256) void gemm_bt128(const unsigned short* __restrict__ A,
                                                  const unsigned short* __restrict__ Bm,
                                                  void* __restrict__ Cc,
                                                  int M, int N, int K) {
  __shared__ unsigned short As[128 * 32];
  __shared__ unsigned short Bs[128 * 32];
  int t = threadIdx.x, lane = t & 63, wave = t >> 6;
  int lm = lane & 15, quad = lane >> 4;
  int wm = wave >> 1, wn = wave & 1;
  int m0 = blockIdx.y * 128, n0 = blockIdx.x * 128;
  int srow = t >> 2;                               // 0..63
  int pcol = (((t & 3) ^ (srow & 3)) * 8);         // swizzled column group (shorts)
  f32x4 acc[4][4] = {};
  const unsigned short* ag = A + (size_t)(m0 + srow) * K + pcol;
  const unsigned short* bg = Bm + (size_t)(n0 + srow) * K + pcol;
  unsigned short* asl = &As[(size_t)t * 8];
  unsigned short* bsl = &Bs[(size_t)t * 8];
  for (int k0 = 0; k0 < K; k0 += 32) {
    __syncthreads();
    gload16(ag + k0, asl);
    gload16(ag + (size_t)64 * K + k0, asl + 2048);
    gload16(bg + k0, bsl);
    gload16(bg + (size_t)64 * K + k0, bsl + 2048);
    __syncthreads();
    int xq = (quad ^ (lm & 3)) * 8;
    short8 af[4], bf[4];
#pragma unroll
    for (int mt = 0; mt < 4; mt++)
      af[mt] = *(const short8*)&As[(wm * 64 + mt * 16 + lm) * 32 + xq];
#pragma unroll
    for (int nt = 0; nt < 4; nt++)
      bf[nt] = *(const short8*)&Bs[(wn * 64 + nt * 16 + lm) * 32 + xq];
#pragma unroll
    for (int mt = 0; mt < 4; mt++)
#pragma unroll
      for (int nt = 0; nt < 4; nt++)
        acc[mt][nt] = __builtin_amdgcn_mfma_f32_16x16x32_bf16(af[mt], bf[nt], acc[mt][nt], 0, 0, 0);
  }
#pragma unroll
  for (int mt = 0; mt < 4; mt++)
#pragma unroll
    for (int nt = 0; nt < 4; nt++)
#pragma unroll
      for (int r = 0; r < 4; r++) {
        size_t row = m0 + wm * 64 + mt * 16 + quad * 4 + r;
        size_t col = n0 + wn * 64 + nt * 16 + lm;
        if (OUT_F32) ((float*)Cc)[row * N + col] = acc[mt][nt][r];
        else ((unsigned short*)Cc)[row * N + col] = f2bf(acc[mt][nt][r]);
      }
}

// ---------------- RoPE in-place on bf16, row stride rstride shorts ----------------
__global__ void rope_kernel(unsigned short* __restrict__ x, const int* __restrict__ pos_ids,
                            int nheads, int rstride) {
  int idx = blockIdx.x * blockDim.x + threadIdx.x;
  int j = idx & 63;
  int h = (idx >> 6) % nheads;
  int row = idx / (64 * nheads);
  int s = row & (SEQ - 1);
  float p = (float)pos_ids[s];
  float inv = exp2f(-(float)j * (13.287712379549449f / 64.0f));
  float f = p * inv;
  float c = cosf(f), sn = sinf(f);
  unsigned short* ptr = x + (size_t)row * rstride + h * HD;
  float x1 = bf2f(ptr[j]), x2 = bf2f(ptr[j + 64]);
  ptr[j]      = f2bf(x1 * c - x2 * sn);
  ptr[j + 64] = f2bf(x2 * c + x1 * sn);
}

// ---------------- V transpose: qkv V-region [row][QKVD] -> [B,NKV,HD,S] ----------------
__global__ void transpose_v(const unsigned short* __restrict__ v, unsigned short* __restrict__ vt) {
  int idx = blockIdx.x * blockDim.x + threadIdx.x;
  int s = idx & (SEQ - 1);
  int d = (idx >> 11) & (HD - 1);
  int kv = (idx >> 18) & (NKV - 1);
  int b = idx >> 21;
  vt[idx] = v[((size_t)(b * SEQ + s)) * QKVD + kv * HD + d];
}

// ---------------- Flash attention v5: operand-swapped S^T = K Q^T, K=32 PV ----------------
// Key-slot permutation pi(slot p*16+q*4+r within 32) -> key q*8+p*4+r is applied ONLY to the
// Ks staging rows. Softmax is permutation-invariant; the permuted score regs
// [sc[2g][0..3], sc[2g+1][0..3]] then form the K=32 MFMA A-fragment (k=quad*8+j) lane-locally,
// and the matching V B-fragment is a contiguous b128 read in ORIGINAL key order.
// Defer-max (THR=8, log2 domain) skips the O-rescale on stable tiles; cvt_pk packs P->bf16.
__global__ __launch_bounds__(256) void attn_kernel(const unsigned short* __restrict__ Q,   // qkv base
                                                   const unsigned short* __restrict__ Kb,  // qkv+4096
                                                   const unsigned short* __restrict__ Vt,  // [B,NKV,HD,S]
                                                   unsigned short* __restrict__ O) {       // [B,S,NH*HD]
  __shared__ unsigned short Ks[64 * 136];   // [slot][d], stride 136 shorts (rows permuted by pi)
  __shared__ unsigned short Vs[128 * 72];   // [d][key], stride 72 shorts (original key order)
  int t = threadIdx.x, wave = t >> 6, lane = t & 63;
  int lm = lane & 15, quad = lane >> 4;
  // XCD-contiguous swizzle: hw ids round-robin XCDs; make each XCD own 128 consecutive
  // logical blocks (= 8 h values -> 2 kv panels, ~2MB K/V working set per 4MB L2).
  int blk0 = blockIdx.x;
  int blk = (blk0 & 7) * 128 + (blk0 >> 3);
  int qt = blk & 15;
  int h = (blk >> 4) & 31;
  int b = blk >> 9;
  int kv = h >> 2;
  int qs0 = qt * 128 + wave * 32;
  const float c = 0.08838834764831845f * 1.4426950408889634f;  // 1/sqrt(128) * log2(e)

  // Q fragments (B-operand: n=q=lm, k=d=quad*8+j)
  short8 aq[2][4];
#pragma unroll
  for (int s = 0; s < 2; s++) {
    const unsigned short* qbase = Q + ((size_t)(b * SEQ + qs0 + s * 16 + lm)) * QKVD + h * HD;
#pragma unroll
    for (int kk = 0; kk < 4; kk++)
      aq[s][kk] = *(const short8*)(qbase + kk * 32 + quad * 8);
  }

  f32x4 acc[2][8] = {};     // O: row=q=quad*4+r, col=d=lm (per tt d-subtile)
  float mrow[2] = {-1e30f, -1e30f};
  float lrow[2] = {0.f, 0.f};
  const unsigned short* kbase = Kb + (size_t)b * SEQ * QKVD + kv * HD;
  const unsigned short* vbase = Vt + ((size_t)(b * NKV + kv)) * HD * SEQ;

  int krow = t >> 4, kcol = (t & 15) * 8;
  int vrow = t >> 3, vcol = (t & 7) * 8;
  // permuted key index per staging row: slot bits [g p q1 q0 r1 r0] -> key [g q1 q0 p r1 r0]
  int keyr[4];
#pragma unroll
  for (int pp = 0; pp < 4; pp++) {
    int srow = pp * 16 + krow;
    keyr[pp] = (srow & 0x20) | ((srow & 0x0C) << 1) | ((srow & 0x10) >> 2) | (srow & 3);
  }

  for (int kblk = 0; kblk < SEQ; kblk += 64) {
    // ---- cooperative coalesced staging (K rows permuted, V untouched) ----
#pragma unroll
    for (int pp = 0; pp < 4; pp++) {
      *(uint4*)&Ks[(pp * 16 + krow) * 136 + kcol] =
          *(const uint4*)(kbase + (size_t)(kblk + keyr[pp]) * QKVD + kcol);
      *(uint4*)&Vs[(pp * 32 + vrow) * 72 + vcol] =
          *(const uint4*)(vbase + (size_t)(pp * 32 + vrow) * SEQ + kblk + vcol);
    }
    __syncthreads();
    // ---- S^T = K Q^T : A = K-frag (m=slot, k=d), B = Q-frag (n=q, k=d) ----
    f32x4 sc[2][4] = {};
    __builtin_amdgcn_s_setprio(1);
#pragma unroll
    for (int kt = 0; kt < 4; kt++) {
#pragma unroll
      for (int kk = 0; kk < 4; kk++) {
        short8 bk = *(const short8*)&Ks[(kt * 16 + lm) * 136 + kk * 32 + quad * 8];
        sc[0][kt] = __builtin_amdgcn_mfma_f32_16x16x32_bf16(bk, aq[0][kk], sc[0][kt], 0, 0, 0);
        sc[1][kt] = __builtin_amdgcn_mfma_f32_16x16x32_bf16(bk, aq[1][kk], sc[1][kt], 0, 0, 0);
      }
    }
    __builtin_amdgcn_s_setprio(0);
    // ---- online softmax (log2 domain); lane owns q-row = lm, slots kt*16+quad*4+r ----
    union PW { uint4v w; short8 h; } pw[2][2];
#pragma unroll
    for (int s = 0; s < 2; s++) {
      float vmax = -1e30f;
#pragma unroll
      for (int kt = 0; kt < 4; kt++)
        vmax = fmaxf(vmax, fmaxf(fmaxf(sc[s][kt][0], sc[s][kt][1]),
                                 fmaxf(sc[s][kt][2], sc[s][kt][3])));
      vmax *= c;
      vmax = fmaxf(vmax, __shfl_xor(vmax, 16));
      vmax = fmaxf(vmax, __shfl_xor(vmax, 32));
      // defer-max: only rescale when some q-row grew past the old max by >8 (P bounded by 2^8)
      if (__any(vmax > mrow[s] + 8.0f)) {
        float nm = fmaxf(mrow[s], vmax);
        float alpha = __builtin_amdgcn_exp2f(mrow[s] - nm);
        mrow[s] = nm;
        lrow[s] *= alpha;
#pragma unroll
        for (int r = 0; r < 4; r++) {
          float ar = __shfl(alpha, quad * 4 + r);
#pragma unroll
          for (int tt = 0; tt < 8; tt++) acc[s][tt][r] *= ar;
        }
      }
      float nm = mrow[s];
      float rs = 0.f;
#pragma unroll
      for (int kt = 0; kt < 4; kt++) {
        float p0 = __builtin_amdgcn_exp2f(sc[s][kt][0] * c - nm);
        float p1 = __builtin_amdgcn_exp2f(sc[s][kt][1] * c - nm);
        float p2 = __builtin_amdgcn_exp2f(sc[s][kt][2] * c - nm);
        float p3 = __builtin_amdgcn_exp2f(sc[s][kt][3] * c - nm);
        rs += (p0 + p1) + (p2 + p3);
        pw[s][kt >> 1].w[(kt & 1) * 2 + 0] = cvtpk(p0, p1);
        pw[s][kt >> 1].w[(kt & 1) * 2 + 1] = cvtpk(p2, p3);
      }
      rs += __shfl_xor(rs, 16);
      rs += __shfl_xor(rs, 32);
      lrow[s] += rs;
    }
    // ---- O += P V via K=32 MFMA, P direct from registers, V as contiguous b128 ----
    __builtin_amdgcn_s_setprio(1);
#pragma unroll
    for (int g = 0; g < 2; g++) {
      short8 ap0 = pw[0][g].h;
      short8 ap1 = pw[1][g].h;
#pragma unroll
      for (int tt = 0; tt < 8; tt++) {
        short8 bv = *(const short8*)&Vs[(tt * 16 + lm) * 72 + g * 32 + quad * 8];
        acc[0][tt] = __builtin_amdgcn_mfma_f32_16x16x32_bf16(ap0, bv, acc[0][tt], 0, 0, 0);
        acc[1][tt] = __builtin_amdgcn_mfma_f32_16x16x32_bf16(ap1, bv, acc[1][tt], 0, 0, 0);
      }
    }
    __builtin_amdgcn_s_setprio(0);
    __syncthreads();
  }
  // epilogue: acc row q=quad*4+r needs l from lane lm=quad*4+r
#pragma unroll
  for (int s = 0; s < 2; s++) {
#pragma unroll
    for (int r = 0; r < 4; r++) {
      float lq = __shfl(lrow[s], quad * 4 + r);
      float inv = 1.0f / lq;
      int row = qs0 + s * 16 + quad * 4 + r;
      unsigned short* op = O + ((size_t)(b * SEQ + row)) * HIDDEN + h * HD;
#pragma unroll
      for (int tt = 0; tt < 8; tt++)
        op[tt * 16 + lm] = f2bf(acc[s][tt][r] * inv);
    }
  }
}

extern "C" void kernel_launch(void* const* d_in, const int* in_sizes, int n_in,
                              void* d_out, int out_size, void* d_ws, size_t ws_size,
                              hipStream_t stream) {
  const float* hidden = (const float*)d_in[0];
  const int*   pos    = (const int*)d_in[1];
  const float* Wq     = (const float*)d_in[2];
  const float* Wk     = (const float*)d_in[3];
  const float* Wv     = (const float*)d_in[4];
  const float* Wo     = (const float*)d_in[5];

  char* ws = (char*)d_ws;
  unsigned short* hx  = (unsigned short*)ws; ws += (size_t)BS * HIDDEN * 2;
  unsigned short* wq  = (unsigned short*)ws; ws += (size_t)HIDDEN * HIDDEN * 2;  // wq,wk,wv contiguous:
  unsigned short* wk  = (unsigned short*)ws; ws += (size_t)1024 * HIDDEN * 2;    //  one [6144,4096] weight
  unsigned short* wv  = (unsigned short*)ws; ws += (size_t)1024 * HIDDEN * 2;
  unsigned short* wo  = (unsigned short*)ws; ws += (size_t)HIDDEN * HIDDEN * 2;
  unsigned short* qkv = (unsigned short*)ws; ws += (size_t)BS * QKVD * 2;        // [BS][6144] merged QKV
  unsigned short* vt  = (unsigned short*)ws; ws += (size_t)BS * 1024 * 2;
  unsigned short* ob  = (unsigned short*)ws; ws += (size_t)BS * HIDDEN * 2;

  cast_f32_bf16<<<16384, 256, 0, stream>>>(hidden, hx);
  cast_f32_bf16<<<16384, 256, 0, stream>>>(Wq, wq);
  cast_f32_bf16<<<4096, 256, 0, stream>>>(Wk, wk);
  cast_f32_bf16<<<4096, 256, 0, stream>>>(Wv, wv);
  cast_f32_bf16<<<16384, 256, 0, stream>>>(Wo, wo);
  // merged QKV projection: N = 4096+1024+1024, single launch, 1536 blocks
  gemm_bt128<0><<<dim3(48, 32), 256, 0, stream>>>(hx, wq, qkv, BS, QKVD, HIDDEN);
  rope_kernel<<<32768, 256, 0, stream>>>(qkv, pos, NH, QKVD);
  rope_kernel<<<8192, 256, 0, stream>>>(qkv + HIDDEN, pos, NKV, QKVD);
  transpose_v<<<16384, 256, 0, stream>>>(qkv + HIDDEN + 1024, vt);
  attn_kernel<<<1024, 256, 0, stream>>>(qkv, qkv + HIDDEN, vt, ob);
  gemm_bt128<1><<<dim3(32, 32), 256, 0, stream>>>(ob, wo, d_out, BS, HIDDEN, HIDDEN);
}

// Round 2
// 892.528 us; speedup vs baseline: 1.3092x; 1.1307x over previous
//
#include <hip/hip_runtime.h>
#include <math.h>

#define HIDDEN 4096
#define NH 32
#define NKV 8
#define HD 128
#define BBATCH 2
#define SEQ 2048
#define BS 4096     // BBATCH*SEQ
#define QKVD 6144   // merged QKV projection row stride (shorts): 4096 Q + 1024 K + 1024 V

typedef __attribute__((ext_vector_type(8))) short short8;
typedef __attribute__((ext_vector_type(4))) float f32x4;
typedef __attribute__((ext_vector_type(4))) unsigned int uint4v;

__device__ __forceinline__ unsigned short f2bf(float f) {
  union { float f; unsigned int u; } v; v.f = f;
  unsigned int r = v.u + 0x7fffu + ((v.u >> 16) & 1u);
  return (unsigned short)(r >> 16);
}
__device__ __forceinline__ float bf2f(unsigned short u) {
  union { unsigned int u; float f; } v; v.u = ((unsigned int)u) << 16;
  return v.f;
}
__device__ __forceinline__ unsigned int cvtpk(float lo, float hi) {
  unsigned int r;
  asm("v_cvt_pk_bf16_f32 %0, %1, %2" : "=v"(r) : "v"(lo), "v"(hi));
  return r;
}

// async global->LDS, 16B per lane. LDS dest must be uniform base + lane*16.
__device__ __forceinline__ void gload16(const unsigned short* g, unsigned short* l) {
  __builtin_amdgcn_global_load_lds((const __attribute__((address_space(1))) unsigned int*)(const void*)g,
                                   (__attribute__((address_space(3))) unsigned int*)(void*)l, 16, 0, 0);
}

// ---------------- fused fp32 -> bf16 cast over all 5 buffers (1 launch) ----------------
// block ranges: hidden 16384 | Wq 16384 | Wk 4096 | Wv 4096 | Wo 16384  = 57344 blocks
__global__ void cast_all(const float* __restrict__ h, const float* __restrict__ q,
                         const float* __restrict__ k, const float* __restrict__ v,
                         const float* __restrict__ o,
                         unsigned short* hx, unsigned short* wq, unsigned short* wk,
                         unsigned short* wv, unsigned short* wo) {
  int b = blockIdx.x;
  const float* src; unsigned short* dst; int base;
  if (b < 16384)      { src = h; dst = hx; base = 0; }
  else if (b < 32768) { src = q; dst = wq; base = 16384; }
  else if (b < 36864) { src = k; dst = wk; base = 32768; }
  else if (b < 40960) { src = v; dst = wv; base = 36864; }
  else                { src = o; dst = wo; base = 40960; }
  size_t i = ((size_t)(b - base) * 256 + threadIdx.x) * 4;
  float4 f = *(const float4*)(src + i);
  ushort4 u;
  u.x = f2bf(f.x); u.y = f2bf(f.y); u.z = f2bf(f.z); u.w = f2bf(f.w);
  *(ushort4*)(dst + i) = u;
}

// ---------------- GEMM m97-style: C[M,N] = A[M,K]*Bm[N,K]^T, 128x128 tile ----------------
template<int OUT_F32>
__global__ __launch_bounds__(256) void gemm_bt128(const unsigned short* __restrict__ A,
                                                  const unsigned short* __restrict__ Bm,
                                                  void* __restrict__ Cc,
                                                  int M, int N, int K) {
  __shared__ unsigned short As[128 * 32];
  __shared__ unsigned short Bs[128 * 32];
  int t = threadIdx.x, lane = t & 63, wave = t >> 6;
  int lm = lane & 15, quad = lane >> 4;
  int wm = wave >> 1, wn = wave & 1;
  int m0 = blockIdx.y * 128, n0 = blockIdx.x * 128;
  int srow = t >> 2;
  int pcol = (((t & 3) ^ (srow & 3)) * 8);
  f32x4 acc[4][4] = {};
  const unsigned short* ag = A + (size_t)(m0 + srow) * K + pcol;
  const unsigned short* bg = Bm + (size_t)(n0 + srow) * K + pcol;
  unsigned short* asl = &As[(size_t)t * 8];
  unsigned short* bsl = &Bs[(size_t)t * 8];
  for (int k0 = 0; k0 < K; k0 += 32) {
    __syncthreads();
    gload16(ag + k0, asl);
    gload16(ag + (size_t)64 * K + k0, asl + 2048);
    gload16(bg + k0, bsl);
    gload16(bg + (size_t)64 * K + k0, bsl + 2048);
    __syncthreads();
    int xq = (quad ^ (lm & 3)) * 8;
    short8 af[4], bf[4];
#pragma unroll
    for (int mt = 0; mt < 4; mt++)
      af[mt] = *(const short8*)&As[(wm * 64 + mt * 16 + lm) * 32 + xq];
#pragma unroll
    for (int nt = 0; nt < 4; nt++)
      bf[nt] = *(const short8*)&Bs[(wn * 64 + nt * 16 + lm) * 32 + xq];
#pragma unroll
    for (int mt = 0; mt < 4; mt++)
#pragma unroll
      for (int nt = 0; nt < 4; nt++)
        acc[mt][nt] = __builtin_amdgcn_mfma_f32_16x16x32_bf16(af[mt], bf[nt], acc[mt][nt], 0, 0, 0);
  }
#pragma unroll
  for (int mt = 0; mt < 4; mt++)
#pragma unroll
    for (int nt = 0; nt < 4; nt++)
#pragma unroll
      for (int r = 0; r < 4; r++) {
        size_t row = m0 + wm * 64 + mt * 16 + quad * 4 + r;
        size_t col = n0 + wn * 64 + nt * 16 + lm;
        if (OUT_F32) ((float*)Cc)[row * N + col] = acc[mt][nt][r];
        else ((unsigned short*)Cc)[row * N + col] = f2bf(acc[mt][nt][r]);
      }
}

// ---------------- RoPE: host-side trig is banned; precompute table once ----------------
__global__ void build_rope_table(const int* __restrict__ pos, float2* __restrict__ cs) {
  int idx = blockIdx.x * blockDim.x + threadIdx.x;  // SEQ*64
  int j = idx & 63, s = idx >> 6;
  float p = (float)pos[s];
  float f = p * exp2f(-(float)j * (13.287712379549449f / 64.0f));
  cs[idx] = make_float2(cosf(f), sinf(f));
}

// fused RoPE over Q (32 heads) + K (8 heads): contiguous head range 0..39 at stride QKVD
__global__ void rope_fused(unsigned short* __restrict__ x, const float2* __restrict__ cs) {
  int idx = blockIdx.x * blockDim.x + threadIdx.x;
  int j = idx & 63;
  int q6 = idx >> 6;
  int hh = q6 % 40;
  int row = q6 / 40;
  int s = row & (SEQ - 1);
  float2 t2 = cs[(s << 6) | j];
  unsigned short* ptr = x + (size_t)row * QKVD + hh * HD;
  float x1 = bf2f(ptr[j]), x2 = bf2f(ptr[j + 64]);
  ptr[j]      = f2bf(x1 * t2.x - x2 * t2.y);
  ptr[j + 64] = f2bf(x2 * t2.x + x1 * t2.y);
}

// ---------------- V transpose, LDS-tiled: qkv V-region [row][QKVD] -> [B,NKV,HD,S] ----------------
__global__ void transpose_v(const unsigned short* __restrict__ v, unsigned short* __restrict__ vt) {
  __shared__ unsigned short tile[64][72];   // 72*2=144B row stride: 16B-aligned, banks spread
  int bx = blockIdx.x;
  int s0 = (bx & 31) * 64;
  int d0 = ((bx >> 5) & 1) * 64;
  int bk = bx >> 6;                  // b*NKV+kv
  int b = bk >> 3, kv = bk & 7;
  int t = threadIdx.x;
  int rs = t >> 2, rc = (t & 3) * 16;
  const unsigned short* src = v + ((size_t)(b * SEQ + s0 + rs)) * QKVD + kv * HD + d0 + rc;
  *(uint4*)&tile[rs][rc]     = *(const uint4*)src;
  *(uint4*)&tile[rs][rc + 8] = *(const uint4*)(src + 8);
  __syncthreads();
  int wd = t >> 2, wc = (t & 3) * 16;
  short8 o0, o1;
#pragma unroll
  for (int e = 0; e < 8; e++) o0[e] = (short)tile[wc + e][wd];
#pragma unroll
  for (int e = 0; e < 8; e++) o1[e] = (short)tile[wc + 8 + e][wd];
  unsigned short* dst = vt + ((size_t)bk * HD + d0 + wd) * SEQ + s0 + wc;
  *(short8*)dst = o0;
  *(short8*)(dst + 8) = o1;
}

// ---------------- Flash attention v6: gload_lds-direct double-buffered pipeline ----------------
// 2-phase minimum pipeline (T3-min): per tile, issue next tile's 8 global_load_lds BEFORE
// computing the current one; single vmcnt(0)+barrier per iteration. LDS layouts are linear
// (gload_lds requirement) with the bank-conflict XOR applied on BOTH sides (rule #21):
// source chunk ^= destrow&7 on the per-lane global address, and chunk ^= row&7 on ds_read.
// K rows additionally carry the slot permutation (srow bits [g p q1 q0 r1 r0] -> key
// [g q1 q0 p r1 r0]) so QK^T score regs form the K=32 PV A-fragment lane-locally.
__global__ __launch_bounds__(256) void attn_kernel(const unsigned short* __restrict__ Q,   // qkv base
                                                   const unsigned short* __restrict__ Kb,  // qkv+4096
                                                   const unsigned short* __restrict__ Vt,  // [B,NKV,HD,S]
                                                   unsigned short* __restrict__ O) {       // [B,S,NH*HD]
  __shared__ unsigned short Ksh[2 * 64 * 128];   // [buf][slot][d], linear
  __shared__ unsigned short Vsh[2 * 128 * 64];   // [buf][d][key], linear
  int t = threadIdx.x, wave = t >> 6, lane = t & 63;
  int lm = lane & 15, quad = lane >> 4;
  int blk0 = blockIdx.x;
  int blk = (blk0 & 7) * 128 + (blk0 >> 3);      // XCD-contiguous (1024 % 8 == 0: bijective)
  int qt = blk & 15;
  int h = (blk >> 4) & 31;
  int b = blk >> 9;
  int kv = h >> 2;
  int qs0 = qt * 128 + wave * 32;
  const float c = 0.08838834764831845f * 1.4426950408889634f;  // 1/sqrt(128) * log2(e)

  // Q fragments (B-operand: n=q=lm, k=d=quad*8+j)
  short8 aq[2][4];
#pragma unroll
  for (int s = 0; s < 2; s++) {
    const unsigned short* qbase = Q + ((size_t)(b * SEQ + qs0 + s * 16 + lm)) * QKVD + h * HD;
#pragma unroll
    for (int kk = 0; kk < 4; kk++)
      aq[s][kk] = *(const short8*)(qbase + kk * 32 + quad * 8);
  }

  f32x4 acc[2][8] = {};
  float mrow[2] = {-1e30f, -1e30f};
  float lrow[2] = {0.f, 0.f};
  const unsigned short* kbase = Kb + (size_t)b * SEQ * QKVD + kv * HD;
  const unsigned short* vbase = Vt + ((size_t)(b * NKV + kv)) * HD * SEQ;

  // staging source pointers (advanced by one tile per iteration)
  int trow = t >> 4;
  int kchunk = (t & 15) ^ (trow & 7);            // inverse-swizzled source chunk
  const unsigned short* ksrc[4];
#pragma unroll
  for (int i = 0; i < 4; i++) {
    int srow = i * 16 + trow;
    int key = (srow & 0x20) | ((srow & 0x0C) << 1) | ((srow & 0x10) >> 2) | (srow & 3);
    ksrc[i] = kbase + (size_t)key * QKVD + kchunk * 8;
  }
  int vrow = t >> 3;
  int vchunk = (t & 7) ^ (vrow & 7);
  const unsigned short* vsrc[4];
#pragma unroll
  for (int i = 0; i < 4; i++)
    vsrc[i] = vbase + (size_t)(i * 32 + vrow) * SEQ + vchunk * 8;

  int xr8 = (lm & 7) * 8;                        // read-side XOR (shorts)

  // prologue: stage tile 0 into buf 0
  {
    unsigned short* kd = Ksh + t * 8;
    unsigned short* vd = Vsh + t * 8;
#pragma unroll
    for (int i = 0; i < 4; i++) gload16(ksrc[i], kd + i * 2048);
#pragma unroll
    for (int i = 0; i < 4; i++) gload16(vsrc[i], vd + i * 2048);
#pragma unroll
    for (int i = 0; i < 4; i++) { ksrc[i] += 64 * QKVD; vsrc[i] += 64; }
  }
  asm volatile("s_waitcnt vmcnt(0)" ::: "memory");
  __syncthreads();

  int cur = 0;
  for (int it = 0; it < SEQ / 64; it++) {
    // issue next tile's loads (overlap with this tile's compute)
    if (it < SEQ / 64 - 1) {
      unsigned short* kd = Ksh + (cur ^ 1) * 8192 + t * 8;
      unsigned short* vd = Vsh + (cur ^ 1) * 8192 + t * 8;
#pragma unroll
      for (int i = 0; i < 4; i++) gload16(ksrc[i], kd + i * 2048);
#pragma unroll
      for (int i = 0; i < 4; i++) gload16(vsrc[i], vd + i * 2048);
#pragma unroll
      for (int i = 0; i < 4; i++) { ksrc[i] += 64 * QKVD; vsrc[i] += 64; }
    }
    const unsigned short* kcur = Ksh + cur * 8192;
    const unsigned short* vcur = Vsh + cur * 8192;
    // ---- S^T = K Q^T ----
    f32x4 sc[2][4] = {};
    __builtin_amdgcn_s_setprio(1);
#pragma unroll
    for (int kt = 0; kt < 4; kt++) {
#pragma unroll
      for (int kk = 0; kk < 4; kk++) {
        short8 bk = *(const short8*)&kcur[(kt * 16 + lm) * 128 + (((kk * 4 + quad) * 8) ^ xr8)];
        sc[0][kt] = __builtin_amdgcn_mfma_f32_16x16x32_bf16(bk, aq[0][kk], sc[0][kt], 0, 0, 0);
        sc[1][kt] = __builtin_amdgcn_mfma_f32_16x16x32_bf16(bk, aq[1][kk], sc[1][kt], 0, 0, 0);
      }
    }
    __builtin_amdgcn_s_setprio(0);
    // ---- online softmax (log2 domain, defer-max THR=8) ----
    union PW { uint4v w; short8 h; } pw[2][2];
#pragma unroll
    for (int s = 0; s < 2; s++) {
      float vmax = -1e30f;
#pragma unroll
      for (int kt = 0; kt < 4; kt++)
        vmax = fmaxf(vmax, fmaxf(fmaxf(sc[s][kt][0], sc[s][kt][1]),
                                 fmaxf(sc[s][kt][2], sc[s][kt][3])));
      vmax *= c;
      vmax = fmaxf(vmax, __shfl_xor(vmax, 16));
      vmax = fmaxf(vmax, __shfl_xor(vmax, 32));
      if (__any(vmax > mrow[s] + 8.0f)) {
        float nm = fmaxf(mrow[s], vmax);
        float alpha = __builtin_amdgcn_exp2f(mrow[s] - nm);
        mrow[s] = nm;
        lrow[s] *= alpha;
#pragma unroll
        for (int r = 0; r < 4; r++) {
          float ar = __shfl(alpha, quad * 4 + r);
#pragma unroll
          for (int tt = 0; tt < 8; tt++) acc[s][tt][r] *= ar;
        }
      }
      float nm = mrow[s];
      float rs = 0.f;
#pragma unroll
      for (int kt = 0; kt < 4; kt++) {
        float p0 = __builtin_amdgcn_exp2f(sc[s][kt][0] * c - nm);
        float p1 = __builtin_amdgcn_exp2f(sc[s][kt][1] * c - nm);
        float p2 = __builtin_amdgcn_exp2f(sc[s][kt][2] * c - nm);
        float p3 = __builtin_amdgcn_exp2f(sc[s][kt][3] * c - nm);
        rs += (p0 + p1) + (p2 + p3);
        pw[s][kt >> 1].w[(kt & 1) * 2 + 0] = cvtpk(p0, p1);
        pw[s][kt >> 1].w[(kt & 1) * 2 + 1] = cvtpk(p2, p3);
      }
      rs += __shfl_xor(rs, 16);
      rs += __shfl_xor(rs, 32);
      lrow[s] += rs;
    }
    // ---- O += P V via K=32 MFMA ----
    __builtin_amdgcn_s_setprio(1);
#pragma unroll
    for (int g = 0; g < 2; g++) {
      short8 ap0 = pw[0][g].h;
      short8 ap1 = pw[1][g].h;
#pragma unroll
      for (int tt = 0; tt < 8; tt++) {
        short8 bv = *(const short8*)&vcur[(tt * 16 + lm) * 64 + (((g * 4 + quad) * 8) ^ xr8)];
        acc[0][tt] = __builtin_amdgcn_mfma_f32_16x16x32_bf16(ap0, bv, acc[0][tt], 0, 0, 0);
        acc[1][tt] = __builtin_amdgcn_mfma_f32_16x16x32_bf16(ap1, bv, acc[1][tt], 0, 0, 0);
      }
    }
    __builtin_amdgcn_s_setprio(0);
    // drain this iteration's prefetch, then single barrier
    asm volatile("s_waitcnt vmcnt(0)" ::: "memory");
    __syncthreads();
    cur ^= 1;
  }
  // epilogue
#pragma unroll
  for (int s = 0; s < 2; s++) {
#pragma unroll
    for (int r = 0; r < 4; r++) {
      float lq = __shfl(lrow[s], quad * 4 + r);
      float inv = 1.0f / lq;
      int row = qs0 + s * 16 + quad * 4 + r;
      unsigned short* op = O + ((size_t)(b * SEQ + row)) * HIDDEN + h * HD;
#pragma unroll
      for (int tt = 0; tt < 8; tt++)
        op[tt * 16 + lm] = f2bf(acc[s][tt][r] * inv);
    }
  }
}

extern "C" void kernel_launch(void* const* d_in, const int* in_sizes, int n_in,
                              void* d_out, int out_size, void* d_ws, size_t ws_size,
                              hipStream_t stream) {
  const float* hidden = (const float*)d_in[0];
  const int*   pos    = (const int*)d_in[1];
  const float* Wq     = (const float*)d_in[2];
  const float* Wk     = (const float*)d_in[3];
  const float* Wv     = (const float*)d_in[4];
  const float* Wo     = (const float*)d_in[5];

  char* ws = (char*)d_ws;
  unsigned short* hx  = (unsigned short*)ws; ws += (size_t)BS * HIDDEN * 2;
  unsigned short* wq  = (unsigned short*)ws; ws += (size_t)HIDDEN * HIDDEN * 2;  // wq,wk,wv contiguous
  unsigned short* wk  = (unsigned short*)ws; ws += (size_t)1024 * HIDDEN * 2;
  unsigned short* wv  = (unsigned short*)ws; ws += (size_t)1024 * HIDDEN * 2;
  unsigned short* wo  = (unsigned short*)ws; ws += (size_t)HIDDEN * HIDDEN * 2;
  unsigned short* qkv = (unsigned short*)ws; ws += (size_t)BS * QKVD * 2;        // [BS][6144]
  unsigned short* vt  = (unsigned short*)ws; ws += (size_t)BS * 1024 * 2;
  unsigned short* ob  = (unsigned short*)ws; ws += (size_t)BS * HIDDEN * 2;
  float2*         cs  = (float2*)ws;         ws += (size_t)SEQ * 64 * sizeof(float2);

  build_rope_table<<<512, 256, 0, stream>>>(pos, cs);
  cast_all<<<57344, 256, 0, stream>>>(hidden, Wq, Wk, Wv, Wo, hx, wq, wk, wv, wo);
  gemm_bt128<0><<<dim3(48, 32), 256, 0, stream>>>(hx, wq, qkv, BS, QKVD, HIDDEN);
  rope_fused<<<40960, 256, 0, stream>>>(qkv, cs);
  transpose_v<<<1024, 256, 0, stream>>>(qkv + HIDDEN + 1024, vt);
  attn_kernel<<<1024, 256, 0, stream>>>(qkv, qkv + HIDDEN, vt, ob);
  gemm_bt128<1><<<dim3(32, 32), 256, 0, stream>>>(ob, wo, d_out, BS, HIDDEN, HIDDEN);
}

// Round 5
// 819.928 us; speedup vs baseline: 1.4251x; 1.0885x over previous
//
#include <hip/hip_runtime.h>
#include <math.h>

#define HIDDEN 4096
#define NH 32
#define NKV 8
#define HD 128
#define BBATCH 2
#define SEQ 2048
#define BS 4096     // BBATCH*SEQ
#define QKVD 6144   // merged QKV projection row stride (shorts): 4096 Q + 1024 K + 1024 V

typedef __attribute__((ext_vector_type(8))) short short8;
typedef __attribute__((ext_vector_type(4))) float f32x4;
typedef __attribute__((ext_vector_type(4))) unsigned int uint4v;

__device__ __forceinline__ unsigned short f2bf(float f) {
  union { float f; unsigned int u; } v; v.f = f;
  unsigned int r = v.u + 0x7fffu + ((v.u >> 16) & 1u);
  return (unsigned short)(r >> 16);
}
__device__ __forceinline__ float bf2f(unsigned short u) {
  union { unsigned int u; float f; } v; v.u = ((unsigned int)u) << 16;
  return v.f;
}
__device__ __forceinline__ unsigned int cvtpk(float lo, float hi) {
  unsigned int r;
  asm("v_cvt_pk_bf16_f32 %0, %1, %2" : "=v"(r) : "v"(lo), "v"(hi));
  return r;
}

// async global->LDS, 16B per lane. LDS dest must be uniform base + lane*16.
__device__ __forceinline__ void gload16(const unsigned short* g, unsigned short* l) {
  __builtin_amdgcn_global_load_lds((const __attribute__((address_space(1))) unsigned int*)(const void*)g,
                                   (__attribute__((address_space(3))) unsigned int*)(void*)l, 16, 0, 0);
}

// ---------------- fused fp32 -> bf16 cast over all 5 buffers (1 launch) ----------------
__global__ void cast_all(const float* __restrict__ h, const float* __restrict__ q,
                         const float* __restrict__ k, const float* __restrict__ v,
                         const float* __restrict__ o,
                         unsigned short* hx, unsigned short* wq, unsigned short* wk,
                         unsigned short* wv, unsigned short* wo) {
  int b = blockIdx.x;
  const float* src; unsigned short* dst; int base;
  if (b < 16384)      { src = h; dst = hx; base = 0; }
  else if (b < 32768) { src = q; dst = wq; base = 16384; }
  else if (b < 36864) { src = k; dst = wk; base = 32768; }
  else if (b < 40960) { src = v; dst = wv; base = 36864; }
  else                { src = o; dst = wo; base = 40960; }
  size_t i = ((size_t)(b - base) * 256 + threadIdx.x) * 4;
  float4 f = *(const float4*)(src + i);
  ushort4 u;
  u.x = f2bf(f.x); u.y = f2bf(f.y); u.z = f2bf(f.z); u.w = f2bf(f.w);
  *(ushort4*)(dst + i) = u;
}

// ---------------- GEMM v2: pipelined 256x256 tile, BK=64, 8 waves ----------------
// C[M,N] = A[M,K] * Bm[N,K]^T.  Double-buffered LDS (128KB, 1 block/CU); all 8
// global_load_lds for tile t+1 issued at the TOP of tile t (issue-to-wait = 64 MFMA/wave
// >> HBM latency); single vmcnt(0)+barrier per K-tile. Never writes the buffer being read.
// LDS linear [256][64] bf16 with both-sides XOR swizzle: chunk ^= row&7 (16B chunks),
// pre-applied on the global source, re-applied on ds_read_b128 -> uniform 8 lanes per
// 4-bank group (minimum). XCD-contiguous block swizzle for A-panel L2 reuse.
template<int OUT_F32>
__global__ __launch_bounds__(512, 2) void gemm_bt256(const unsigned short* __restrict__ A,
                                                     const unsigned short* __restrict__ Bm,
                                                     void* __restrict__ Cc,
                                                     int M, int N, int K) {
  __shared__ unsigned short As[2][256 * 64];
  __shared__ unsigned short Bs[2][256 * 64];
  int t = threadIdx.x, lane = t & 63, wave = t >> 6;
  int lm = lane & 15, quad = lane >> 4;
  int wm = wave >> 2, wn = wave & 3;          // 2 (M) x 4 (N) waves; per-wave C: 128x64
  // XCD-contiguous swizzle (nwg % 8 == 0 for both call sites -> bijective)
  int nwg = gridDim.x * gridDim.y;
  int id = blockIdx.y * gridDim.x + blockIdx.x;
  int cpx = nwg >> 3;
  int sw = (id & 7) * cpx + (id >> 3);
  int bx = sw % gridDim.x, by = sw / gridDim.x;
  int m0 = by * 256, n0 = bx * 256;

  // staging: round i covers rows [64i,64i+64); thread t -> row 64i+(t>>3), LDS chunk t&7,
  // global chunk (t&7)^(row&7)
  int srow = t >> 3;
  int schunk = ((t & 7) ^ (srow & 7)) * 8;
  const unsigned short* ag = A + (size_t)(m0 + srow) * K + schunk;
  const unsigned short* bg = Bm + (size_t)(n0 + srow) * K + schunk;

  f32x4 acc[8][4] = {};

  // prologue: stage tile 0 into buf 0
#pragma unroll
  for (int i = 0; i < 4; i++) gload16(ag + (size_t)i * 64 * K, &As[0][i * 4096 + t * 8]);
#pragma unroll
  for (int i = 0; i < 4; i++) gload16(bg + (size_t)i * 64 * K, &Bs[0][i * 4096 + t * 8]);
  asm volatile("s_waitcnt vmcnt(0)" ::: "memory");
  __syncthreads();

  int cur = 0;
  for (int k0 = 0; k0 < K; k0 += 64) {
    // issue ALL of tile t+1's loads first (max issue-to-wait distance)
    if (k0 + 64 < K) {
#pragma unroll
      for (int i = 0; i < 4; i++)
        gload16(ag + (size_t)i * 64 * K + k0 + 64, &As[cur ^ 1][i * 4096 + t * 8]);
#pragma unroll
      for (int i = 0; i < 4; i++)
        gload16(bg + (size_t)i * 64 * K + k0 + 64, &Bs[cur ^ 1][i * 4096 + t * 8]);
    }
    // B fragments for this wave's 64 cols (4 n-frags x 2 k-steps)
    short8 bfr[4][2];
#pragma unroll
    for (int n = 0; n < 4; n++)
#pragma unroll
      for (int ks = 0; ks < 2; ks++)
        bfr[n][ks] = *(const short8*)&Bs[cur][(wn * 64 + n * 16 + lm) * 64 +
                                             (((ks * 4 + quad) ^ (lm & 7)) * 8)];
    // two half-phases over M (4 m-frags each)
#pragma unroll
    for (int mh = 0; mh < 2; mh++) {
      short8 afr[4][2];
#pragma unroll
      for (int m4 = 0; m4 < 4; m4++)
#pragma unroll
        for (int ks = 0; ks < 2; ks++)
          afr[m4][ks] = *(const short8*)&As[cur][(wm * 128 + (mh * 4 + m4) * 16 + lm) * 64 +
                                                (((ks * 4 + quad) ^ (lm & 7)) * 8)];
      __builtin_amdgcn_s_setprio(1);
#pragma unroll
      for (int m4 = 0; m4 < 4; m4++)
#pragma unroll
        for (int n = 0; n < 4; n++)
#pragma unroll
          for (int ks = 0; ks < 2; ks++)
            acc[mh * 4 + m4][n] =
                __builtin_amdgcn_mfma_f32_16x16x32_bf16(afr[m4][ks], bfr[n][ks],
                                                        acc[mh * 4 + m4][n], 0, 0, 0);
      __builtin_amdgcn_s_setprio(0);
    }
    asm volatile("s_waitcnt vmcnt(0)" ::: "memory");
    __syncthreads();
    cur ^= 1;
  }
  // epilogue: C row = m0 + wm*128 + m*16 + quad*4 + r, col = n0 + wn*64 + n*16 + lm
#pragma unroll
  for (int m = 0; m < 8; m++)
#pragma unroll
    for (int n = 0; n < 4; n++)
#pragma unroll
      for (int r = 0; r < 4; r++) {
        size_t row = m0 + wm * 128 + m * 16 + quad * 4 + r;
        size_t col = n0 + wn * 64 + n * 16 + lm;
        if (OUT_F32) ((float*)Cc)[row * N + col] = acc[m][n][r];
        else ((unsigned short*)Cc)[row * N + col] = f2bf(acc[m][n][r]);
      }
}

// ---------------- RoPE table + fused apply ----------------
__global__ void build_rope_table(const int* __restrict__ pos, float2* __restrict__ cs) {
  int idx = blockIdx.x * blockDim.x + threadIdx.x;  // SEQ*64
  int j = idx & 63, s = idx >> 6;
  float p = (float)pos[s];
  float f = p * exp2f(-(float)j * (13.287712379549449f / 64.0f));
  cs[idx] = make_float2(cosf(f), sinf(f));
}

__global__ void rope_fused(unsigned short* __restrict__ x, const float2* __restrict__ cs) {
  int idx = blockIdx.x * blockDim.x + threadIdx.x;
  int j = idx & 63;
  int q6 = idx >> 6;
  int hh = q6 % 40;
  int row = q6 / 40;
  int s = row & (SEQ - 1);
  float2 t2 = cs[(s << 6) | j];
  unsigned short* ptr = x + (size_t)row * QKVD + hh * HD;
  float x1 = bf2f(ptr[j]), x2 = bf2f(ptr[j + 64]);
  ptr[j]      = f2bf(x1 * t2.x - x2 * t2.y);
  ptr[j + 64] = f2bf(x2 * t2.x + x1 * t2.y);
}

// ---------------- V transpose, LDS-tiled ----------------
__global__ void transpose_v(const unsigned short* __restrict__ v, unsigned short* __restrict__ vt) {
  __shared__ unsigned short tile[64][72];
  int bx = blockIdx.x;
  int s0 = (bx & 31) * 64;
  int d0 = ((bx >> 5) & 1) * 64;
  int bk = bx >> 6;                  // b*NKV+kv
  int b = bk >> 3, kv = bk & 7;
  int t = threadIdx.x;
  int rs = t >> 2, rc = (t & 3) * 16;
  const unsigned short* src = v + ((size_t)(b * SEQ + s0 + rs)) * QKVD + kv * HD + d0 + rc;
  *(uint4*)&tile[rs][rc]     = *(const uint4*)src;
  *(uint4*)&tile[rs][rc + 8] = *(const uint4*)(src + 8);
  __syncthreads();
  int wd = t >> 2, wc = (t & 3) * 16;
  short8 o0, o1;
#pragma unroll
  for (int e = 0; e < 8; e++) o0[e] = (short)tile[wc + e][wd];
#pragma unroll
  for (int e = 0; e < 8; e++) o1[e] = (short)tile[wc + 8 + e][wd];
  unsigned short* dst = vt + ((size_t)bk * HD + d0 + wd) * SEQ + s0 + wc;
  *(short8*)dst = o0;
  *(short8*)(dst + 8) = o1;
}

// ---------------- Flash attention v6: gload_lds-direct double-buffered pipeline ----------------
__global__ __launch_bounds__(256) void attn_kernel(const unsigned short* __restrict__ Q,   // qkv base
                                                   const unsigned short* __restrict__ Kb,  // qkv+4096
                                                   const unsigned short* __restrict__ Vt,  // [B,NKV,HD,S]
                                                   unsigned short* __restrict__ O) {       // [B,S,NH*HD]
  __shared__ unsigned short Ksh[2 * 64 * 128];   // [buf][slot][d], linear
  __shared__ unsigned short Vsh[2 * 128 * 64];   // [buf][d][key], linear
  int t = threadIdx.x, wave = t >> 6, lane = t & 63;
  int lm = lane & 15, quad = lane >> 4;
  int blk0 = blockIdx.x;
  int blk = (blk0 & 7) * 128 + (blk0 >> 3);      // XCD-contiguous (1024 % 8 == 0: bijective)
  int qt = blk & 15;
  int h = (blk >> 4) & 31;
  int b = blk >> 9;
  int kv = h >> 2;
  int qs0 = qt * 128 + wave * 32;
  const float c = 0.08838834764831845f * 1.4426950408889634f;  // 1/sqrt(128) * log2(e)

  // Q fragments (B-operand: n=q=lm, k=d=quad*8+j)
  short8 aq[2][4];
#pragma unroll
  for (int s = 0; s < 2; s++) {
    const unsigned short* qbase = Q + ((size_t)(b * SEQ + qs0 + s * 16 + lm)) * QKVD + h * HD;
#pragma unroll
    for (int kk = 0; kk < 4; kk++)
      aq[s][kk] = *(const short8*)(qbase + kk * 32 + quad * 8);
  }

  f32x4 acc[2][8] = {};
  float mrow[2] = {-1e30f, -1e30f};
  float lrow[2] = {0.f, 0.f};
  const unsigned short* kbase = Kb + (size_t)b * SEQ * QKVD + kv * HD;
  const unsigned short* vbase = Vt + ((size_t)(b * NKV + kv)) * HD * SEQ;

  int trow = t >> 4;
  int kchunk = (t & 15) ^ (trow & 7);
  const unsigned short* ksrc[4];
#pragma unroll
  for (int i = 0; i < 4; i++) {
    int srow = i * 16 + trow;
    int key = (srow & 0x20) | ((srow & 0x0C) << 1) | ((srow & 0x10) >> 2) | (srow & 3);
    ksrc[i] = kbase + (size_t)key * QKVD + kchunk * 8;
  }
  int vrow = t >> 3;
  int vchunk = (t & 7) ^ (vrow & 7);
  const unsigned short* vsrc[4];
#pragma unroll
  for (int i = 0; i < 4; i++)
    vsrc[i] = vbase + (size_t)(i * 32 + vrow) * SEQ + vchunk * 8;

  int xr8 = (lm & 7) * 8;

  // prologue: stage tile 0 into buf 0
  {
    unsigned short* kd = Ksh + t * 8;
    unsigned short* vd = Vsh + t * 8;
#pragma unroll
    for (int i = 0; i < 4; i++) gload16(ksrc[i], kd + i * 2048);
#pragma unroll
    for (int i = 0; i < 4; i++) gload16(vsrc[i], vd + i * 2048);
#pragma unroll
    for (int i = 0; i < 4; i++) { ksrc[i] += 64 * QKVD; vsrc[i] += 64; }
  }
  asm volatile("s_waitcnt vmcnt(0)" ::: "memory");
  __syncthreads();

  int cur = 0;
  for (int it = 0; it < SEQ / 64; it++) {
    if (it < SEQ / 64 - 1) {
      unsigned short* kd = Ksh + (cur ^ 1) * 8192 + t * 8;
      unsigned short* vd = Vsh + (cur ^ 1) * 8192 + t * 8;
#pragma unroll
      for (int i = 0; i < 4; i++) gload16(ksrc[i], kd + i * 2048);
#pragma unroll
      for (int i = 0; i < 4; i++) gload16(vsrc[i], vd + i * 2048);
#pragma unroll
      for (int i = 0; i < 4; i++) { ksrc[i] += 64 * QKVD; vsrc[i] += 64; }
    }
    const unsigned short* kcur = Ksh + cur * 8192;
    const unsigned short* vcur = Vsh + cur * 8192;
    f32x4 sc[2][4] = {};
    __builtin_amdgcn_s_setprio(1);
#pragma unroll
    for (int kt = 0; kt < 4; kt++) {
#pragma unroll
      for (int kk = 0; kk < 4; kk++) {
        short8 bk = *(const short8*)&kcur[(kt * 16 + lm) * 128 + (((kk * 4 + quad) * 8) ^ xr8)];
        sc[0][kt] = __builtin_amdgcn_mfma_f32_16x16x32_bf16(bk, aq[0][kk], sc[0][kt], 0, 0, 0);
        sc[1][kt] = __builtin_amdgcn_mfma_f32_16x16x32_bf16(bk, aq[1][kk], sc[1][kt], 0, 0, 0);
      }
    }
    __builtin_amdgcn_s_setprio(0);
    union PW { uint4v w; short8 h; } pw[2][2];
#pragma unroll
    for (int s = 0; s < 2; s++) {
      float vmax = -1e30f;
#pragma unroll
      for (int kt = 0; kt < 4; kt++)
        vmax = fmaxf(vmax, fmaxf(fmaxf(sc[s][kt][0], sc[s][kt][1]),
                                 fmaxf(sc[s][kt][2], sc[s][kt][3])));
      vmax *= c;
      vmax = fmaxf(vmax, __shfl_xor(vmax, 16));
      vmax = fmaxf(vmax, __shfl_xor(vmax, 32));
      if (__any(vmax > mrow[s] + 8.0f)) {
        float nm = fmaxf(mrow[s], vmax);
        float alpha = __builtin_amdgcn_exp2f(mrow[s] - nm);
        mrow[s] = nm;
        lrow[s] *= alpha;
#pragma unroll
        for (int r = 0; r < 4; r++) {
          float ar = __shfl(alpha, quad * 4 + r);
#pragma unroll
          for (int tt = 0; tt < 8; tt++) acc[s][tt][r] *= ar;
        }
      }
      float nm = mrow[s];
      float rs = 0.f;
#pragma unroll
      for (int kt = 0; kt < 4; kt++) {
        float p0 = __builtin_amdgcn_exp2f(sc[s][kt][0] * c - nm);
        float p1 = __builtin_amdgcn_exp2f(sc[s][kt][1] * c - nm);
        float p2 = __builtin_amdgcn_exp2f(sc[s][kt][2] * c - nm);
        float p3 = __builtin_amdgcn_exp2f(sc[s][kt][3] * c - nm);
        rs += (p0 + p1) + (p2 + p3);
        pw[s][kt >> 1].w[(kt & 1) * 2 + 0] = cvtpk(p0, p1);
        pw[s][kt >> 1].w[(kt & 1) * 2 + 1] = cvtpk(p2, p3);
      }
      rs += __shfl_xor(rs, 16);
      rs += __shfl_xor(rs, 32);
      lrow[s] += rs;
    }
    __builtin_amdgcn_s_setprio(1);
#pragma unroll
    for (int g = 0; g < 2; g++) {
      short8 ap0 = pw[0][g].h;
      short8 ap1 = pw[1][g].h;
#pragma unroll
      for (int tt = 0; tt < 8; tt++) {
        short8 bv = *(const short8*)&vcur[(tt * 16 + lm) * 64 + (((g * 4 + quad) * 8) ^ xr8)];
        acc[0][tt] = __builtin_amdgcn_mfma_f32_16x16x32_bf16(ap0, bv, acc[0][tt], 0, 0, 0);
        acc[1][tt] = __builtin_amdgcn_mfma_f32_16x16x32_bf16(ap1, bv, acc[1][tt], 0, 0, 0);
      }
    }
    __builtin_amdgcn_s_setprio(0);
    asm volatile("s_waitcnt vmcnt(0)" ::: "memory");
    __syncthreads();
    cur ^= 1;
  }
#pragma unroll
  for (int s = 0; s < 2; s++) {
#pragma unroll
    for (int r = 0; r < 4; r++) {
      float lq = __shfl(lrow[s], quad * 4 + r);
      float inv = 1.0f / lq;
      int row = qs0 + s * 16 + quad * 4 + r;
      unsigned short* op = O + ((size_t)(b * SEQ + row)) * HIDDEN + h * HD;
#pragma unroll
      for (int tt = 0; tt < 8; tt++)
        op[tt * 16 + lm] = f2bf(acc[s][tt][r] * inv);
    }
  }
}

extern "C" void kernel_launch(void* const* d_in, const int* in_sizes, int n_in,
                              void* d_out, int out_size, void* d_ws, size_t ws_size,
                              hipStream_t stream) {
  const float* hidden = (const float*)d_in[0];
  const int*   pos    = (const int*)d_in[1];
  const float* Wq     = (const float*)d_in[2];
  const float* Wk     = (const float*)d_in[3];
  const float* Wv     = (const float*)d_in[4];
  const float* Wo     = (const float*)d_in[5];

  char* ws = (char*)d_ws;
  unsigned short* hx  = (unsigned short*)ws; ws += (size_t)BS * HIDDEN * 2;
  unsigned short* wq  = (unsigned short*)ws; ws += (size_t)HIDDEN * HIDDEN * 2;  // wq,wk,wv contiguous
  unsigned short* wk  = (unsigned short*)ws; ws += (size_t)1024 * HIDDEN * 2;
  unsigned short* wv  = (unsigned short*)ws; ws += (size_t)1024 * HIDDEN * 2;
  unsigned short* wo  = (unsigned short*)ws; ws += (size_t)HIDDEN * HIDDEN * 2;
  unsigned short* qkv = (unsigned short*)ws; ws += (size_t)BS * QKVD * 2;        // [BS][6144]
  unsigned short* vt  = (unsigned short*)ws; ws += (size_t)BS * 1024 * 2;
  unsigned short* ob  = (unsigned short*)ws; ws += (size_t)BS * HIDDEN * 2;
  float2*         cs  = (float2*)ws;         ws += (size_t)SEQ * 64 * sizeof(float2);

  build_rope_table<<<512, 256, 0, stream>>>(pos, cs);
  cast_all<<<57344, 256, 0, stream>>>(hidden, Wq, Wk, Wv, Wo, hx, wq, wk, wv, wo);
  gemm_bt256<0><<<dim3(24, 16), 512, 0, stream>>>(hx, wq, qkv, BS, QKVD, HIDDEN);
  rope_fused<<<40960, 256, 0, stream>>>(qkv, cs);
  transpose_v<<<1024, 256, 0, stream>>>(qkv + HIDDEN + 1024, vt);
  attn_kernel<<<1024, 256, 0, stream>>>(qkv, qkv + HIDDEN, vt, ob);
  gemm_bt256<1><<<dim3(16, 16), 512, 0, stream>>>(ob, wo, d_out, BS, HIDDEN, HIDDEN);
}